// Round 12
// baseline (2465.080 us; speedup 1.0000x reference)
//
#include <hip/hip_runtime.h>

using us = unsigned short;
typedef short short8v __attribute__((ext_vector_type(8)));
typedef float float4v __attribute__((ext_vector_type(4)));

// ---------------- problem constants ----------------
constexpr int NB  = 4;
constexpr int NT  = 512;
constexpr int ND  = 1024;
constexpr int NL  = 12;
constexpr int NH  = 16;
constexpr int NF  = 4096;
constexpr int NHD = 64;
constexpr int NBT = NB * NT;   // 2048
constexpr int NV  = 32000;
constexpr long QOFF = (long)NBT * ND;  // qw|qr|k stride in qkvbuf
constexpr long RKL  = 640L * 1024;     // per-layer rk stride (rows 512.. are zero pad)

__device__ __forceinline__ us f2bf(float f) {
    unsigned u = __float_as_uint(f);
    u += 0x7fffu + ((u >> 16) & 1u);      // RNE
    return (us)(u >> 16);
}

// async global->LDS, 16B per lane. LDS dest is wave-uniform base + lane*16;
// global src is per-lane (pre-swizzled for bank-conflict-free ds_read).
__device__ __forceinline__ void gload16(const us* g, us* l) {
    __builtin_amdgcn_global_load_lds(
        (const __attribute__((address_space(1))) void*)g,
        (__attribute__((address_space(3))) void*)l, 16, 0, 0);
}

// =====================================================================
// bf16 MFMA GEMM:  C[M,N] = A[M,K] @ B[N,K]^T   (both row-major, k-contig)
// 256 threads = 4 waves (2x2), per-wave tile (BM/2)x(BN/2), BK=64.
// TWO-PHASE double-buffered staging (prefetch next tile under MFMA).
// EPI: 0 plain (+bias,+addsrc), 1 gelu, 3 fused QKV epilogue:
//      seg0 -> qw,qr (+r_w/r_r bias), seg1 -> k, seg2 -> vt[b,h,d,t] packed.
// =====================================================================
template<int BM, int BN, int EPI, bool OUTBF>
__global__ __launch_bounds__(256)
void bgemm_k(const us* __restrict__ A, const us* __restrict__ B, void* Cv,
             const float* __restrict__ bias, const float* addsrc,
             const float* __restrict__ p0, const float* __restrict__ p1,
             us* __restrict__ vtp,
             int N, int K, int lda, int ldb, int ldc,
             int bdiv, long sAb, long sAh, long sBb, long sBh, long sCb, long sCh)
{
    constexpr int BK  = 64;
    constexpr int WTM = BM / 2, WTN = BN / 2;
    constexpr int FM  = WTM / 16, FN = WTN / 16;
    constexpr int AI  = BM / 32;       // gload16 instr per wave (A tile)
    constexpr int BI  = BN / 32;
    static_assert(BM % 32 == 0 && BN % 32 == 0, "");

    long coff = 0;
    if (bdiv > 0) {
        int z = blockIdx.z, zb = z / bdiv, zh = z % bdiv;
        A += zb * sAb + zh * sAh;
        B += zb * sBb + zh * sBh;
        coff = zb * sCb + zh * sCh;
    }
    float* Cf = (float*)Cv + coff;
    us*    Ch = (us*)Cv + coff;
    if (addsrc) addsrc += coff;

    __shared__ __align__(16) us As[2 * BM * BK];
    __shared__ __align__(16) us Bs[2 * BN * BK];

    const int tid  = threadIdx.x;
    const int lane = tid & 63;
    const int w    = tid >> 6;
    const int wm   = w >> 1;
    const int wn   = w & 1;
    const int row0 = blockIdx.y * BM;
    const int col0 = blockIdx.x * BN;

    float4v acc[FM][FN];
#pragma unroll
    for (int i = 0; i < FM; ++i)
#pragma unroll
        for (int j = 0; j < FN; ++j) acc[i][j] = (float4v)0.f;

    auto stage = [&](int buf, int k0) {
        us* Ad = As + buf * (BM * BK);
        us* Bd = Bs + buf * (BN * BK);
#pragma unroll
        for (int i = 0; i < AI; ++i) {
            int rb = w * (BM / 4) + i * 8;
            int r  = rb + (lane >> 3);
            int sc8 = ((lane & 7) ^ (r & 7)) << 3;
            gload16(A + (long)(row0 + r) * lda + k0 + sc8, Ad + rb * 64);
        }
#pragma unroll
        for (int i = 0; i < BI; ++i) {
            int rb = w * (BN / 4) + i * 8;
            int r  = rb + (lane >> 3);
            int sc8 = ((lane & 7) ^ (r & 7)) << 3;
            gload16(B + (long)(col0 + r) * ldb + k0 + sc8, Bd + rb * 64);
        }
    };

    stage(0, 0);
    __syncthreads();           // buf0 staged (vmcnt drained)
    int cur = 0;
    for (int k0 = 0; k0 < K; k0 += BK) {
        if (k0 + BK < K) stage(cur ^ 1, k0 + BK);   // prefetch next tile
        const char* Ac = (const char*)(As + cur * (BM * BK));
        const char* Bc = (const char*)(Bs + cur * (BN * BK));
#pragma unroll
        for (int ks = 0; ks < 2; ++ks) {
            short8v af[FM], bfr[FN];
            int sw = ks * 4 + (lane >> 4);
#pragma unroll
            for (int i = 0; i < FM; ++i) {
                int r = wm * WTM + i * 16 + (lane & 15);
                af[i] = *reinterpret_cast<const short8v*>(Ac + r * 128 + ((sw ^ (r & 7)) << 4));
            }
#pragma unroll
            for (int j = 0; j < FN; ++j) {
                int r = wn * WTN + j * 16 + (lane & 15);
                bfr[j] = *reinterpret_cast<const short8v*>(Bc + r * 128 + ((sw ^ (r & 7)) << 4));
            }
#pragma unroll
            for (int i = 0; i < FM; ++i)
#pragma unroll
                for (int j = 0; j < FN; ++j)
                    acc[i][j] = __builtin_amdgcn_mfma_f32_16x16x32_bf16(af[i], bfr[j], acc[i][j], 0, 0, 0);
        }
        __syncthreads();       // next tile staged; all waves done reading cur
        cur ^= 1;
    }

    // ---- epilogue.  D layout: col = lane&15, row = (lane>>4)*4 + reg ----
#pragma unroll
    for (int i = 0; i < FM; ++i) {
        int growb = row0 + wm * WTM + i * 16 + ((lane >> 4) << 2);
#pragma unroll
        for (int j = 0; j < FN; ++j) {
            int gcol = col0 + wn * WTN + j * 16 + (lane & 15);
            if (EPI == 3) {
                int seg = gcol >> 10, c = gcol & 1023;
                float bb = bias[gcol];
                if (seg == 2) {
                    // v -> vt[b,h,d,t], 4 consecutive t packed into 8B
                    unsigned lo = (unsigned)f2bf(acc[i][j][0] + bb)
                                | ((unsigned)f2bf(acc[i][j][1] + bb) << 16);
                    unsigned hi = (unsigned)f2bf(acc[i][j][2] + bb)
                                | ((unsigned)f2bf(acc[i][j][3] + bb) << 16);
                    int bidx = growb >> 9, tb = growb & 511;
                    uint2 pk; pk.x = lo; pk.y = hi;
                    *reinterpret_cast<uint2*>(
                        vtp + ((long)((bidx * 16 + (c >> 6)) * 64 + (c & 63)) << 9) + tb) = pk;
                } else {
                    us* base = (us*)Cv;
#pragma unroll
                    for (int r = 0; r < 4; ++r) {
                        int gr = growb + r;
                        float v = acc[i][j][r] + bb;
                        long o = (long)gr * 1024 + c;
                        if (seg == 0) {
                            base[o]        = f2bf(v + p0[c]);   // qw
                            base[o + QOFF] = f2bf(v + p1[c]);   // qr
                        } else base[o + 2 * QOFF] = f2bf(v);    // k
                    }
                }
            } else {
                if (gcol >= N) continue;
#pragma unroll
                for (int r = 0; r < 4; ++r) {
                    int gr = growb + r;
                    float v = acc[i][j][r];
                    if (bias) v += bias[gcol];
                    if (EPI == 1) {
                        float xx = v;
                        v = 0.5f * xx * (1.f + tanhf(0.7978845608028654f
                                                     * (xx + 0.044715f * xx * xx * xx)));
                    }
                    if (addsrc) v += addsrc[(long)gr * ldc + gcol];
                    if (OUTBF) Ch[(long)gr * ldc + gcol] = f2bf(v);
                    else       Cf[(long)gr * ldc + gcol] = v;
                }
            }
        }
    }
}

// =====================================================================
// Fused split-K reduce + residual + (LN -> bf16 | bf16 convert).
// =====================================================================
template<int NPART, int MODE>
__global__ __launch_bounds__(256)
void redln_k(const float* __restrict__ part, const float* __restrict__ bias,
             float* __restrict__ h, us* __restrict__ outb,
             const float* __restrict__ sc, const float* __restrict__ bi)
{
    int row = blockIdx.x;
    int d4 = threadIdx.x * 4;
    long i = (long)row * ND + d4;
    float4 hv = *reinterpret_cast<const float4*>(h + i);
    float4 bb = *reinterpret_cast<const float4*>(bias + d4);
    hv.x += bb.x; hv.y += bb.y; hv.z += bb.z; hv.w += bb.w;
#pragma unroll
    for (int z = 0; z < NPART; ++z) {
        float4 a = *reinterpret_cast<const float4*>(part + (long)z * 2097152 + i);
        hv.x += a.x; hv.y += a.y; hv.z += a.z; hv.w += a.w;
    }
    *reinterpret_cast<float4*>(h + i) = hv;
    if (MODE == 1) {
        uint2 p;
        p.x = (unsigned)f2bf(hv.x) | ((unsigned)f2bf(hv.y) << 16);
        p.y = (unsigned)f2bf(hv.z) | ((unsigned)f2bf(hv.w) << 16);
        *reinterpret_cast<uint2*>(outb + i) = p;
    } else {
        float sum = hv.x + hv.y + hv.z + hv.w;
        float sq  = hv.x * hv.x + hv.y * hv.y + hv.z * hv.z + hv.w * hv.w;
#pragma unroll
        for (int o = 32; o; o >>= 1) { sum += __shfl_xor(sum, o); sq += __shfl_xor(sq, o); }
        __shared__ float red[8];
        int w = threadIdx.x >> 6;
        if ((threadIdx.x & 63) == 0) { red[w] = sum; red[4 + w] = sq; }
        __syncthreads();
        sum = red[0] + red[1] + red[2] + red[3];
        sq  = red[4] + red[5] + red[6] + red[7];
        float mean = sum * (1.f / ND);
        float var  = fmaxf(sq * (1.f / ND) - mean * mean, 0.f);
        float inv  = rsqrtf(var + 1e-5f);
        float4 s4 = *reinterpret_cast<const float4*>(&sc[d4]);
        float4 b4 = *reinterpret_cast<const float4*>(&bi[d4]);
        uint2 p;
        p.x = (unsigned)f2bf((hv.x - mean) * inv * s4.x + b4.x)
            | ((unsigned)f2bf((hv.y - mean) * inv * s4.y + b4.y) << 16);
        p.y = (unsigned)f2bf((hv.z - mean) * inv * s4.z + b4.z)
            | ((unsigned)f2bf((hv.w - mean) * inv * s4.w + b4.w) << 16);
        *reinterpret_cast<uint2*>(outb + i) = p;
    }
}

// =====================================================================
// Fused TXL attention, ROLLING rel band, paired q-tiles, 2-WAY KV SPLIT:
// block (qtp, bh, hf) processes q-tiles {qtp, 7-qtp}; for each, only the
// hf-half of its kv-step range [st_s, st_e).  Writes UNNORMALIZED O (fp32)
// + per-row m,l partials; amerge_k combines the halves.
// 512 blocks, 66KB LDS -> 2 blocks/CU co-resident (2 waves/SIMD).
// Empty half (qt==0, hf==1) writes identity partials (m=-3e38,l=0,O=0).
// =====================================================================
__global__ __launch_bounds__(256)
void fattn_k(const us* __restrict__ qkv, const us* __restrict__ vt,
             const us* __restrict__ rk, float* __restrict__ pO,
             float* __restrict__ pm, float* __restrict__ pl)
{
    __shared__ __align__(16) us lds_k[64 * 64];
    __shared__ __align__(16) us lds_v[64 * 64];
    __shared__ __align__(16) us lds_rk[64 * 64];
    __shared__ __align__(16) us lds_p[4 * 16 * 64];
    __shared__ float lds_r[4 * 16 * 132];       // per-wave R, row stride 132

    const int tid = threadIdx.x, lane = tid & 63, w = tid >> 6;
    const int qtp = blockIdx.x, bh = blockIdx.y, hf = blockIdx.z;
    const int b = bh >> 4, h = bh & 15;
    const int rg = lane >> 4, lc = lane & 15;

    const us* qwb = qkv + ((long)b * 512) * 1024 + h * 64;   // row stride 1024
    const us* qrb = qwb + QOFF;
    const us* kb  = qwb + 2 * QOFF;
    const us* vtb = vt + (long)bh * 64 * 512;                // rows d, stride 512
    const us* rkb = rk + h * 64;                             // rows j, stride 1024

    float* rbase = lds_r + w * (16 * 132);
    us*    pbase = lds_p + w * (16 * 64);

    auto stage_rk = [&](int j0) {
#pragma unroll
        for (int i = 0; i < 2; ++i) {
            int rb = w * 16 + i * 8;
            int r  = rb + (lane >> 3);
            int sl = ((lane & 7) ^ (r & 7)) << 3;
            gload16(rkb + (long)(j0 + r) * 1024 + sl, lds_rk + rb * 64);
        }
    };

    for (int hh = 0; hh < 2; ++hh) {
        const int qt = hh ? 7 - qtp : qtp;
        const int t0 = qt * 64;
        const int n  = qt + 1;
        const int h0 = (n + 1) >> 1;
        const int st_s = hf ? h0 : 0;
        const int st_e = hf ? n  : h0;

        // Q fragments (rows t0 + w*16 + lc, k-slices kk*32 + rg*8)
        short8v aqw[2], aqr[2];
        {
            long qrow = (long)(t0 + w * 16 + lc) * 1024;
            int ko = rg * 8;
            aqw[0] = *(const short8v*)(qwb + qrow + ko);
            aqw[1] = *(const short8v*)(qwb + qrow + 32 + ko);
            aqr[0] = *(const short8v*)(qrb + qrow + ko);
            aqr[1] = *(const short8v*)(qrb + qrow + 32 + ko);
        }

        float4v oacc[4];
#pragma unroll
        for (int i = 0; i < 4; ++i) oacc[i] = (float4v)0.f;
        float mrow[4] = {-3e38f, -3e38f, -3e38f, -3e38f};
        float lrow[4] = {0.f, 0.f, 0.f, 0.f};

        auto rel_half = [&](int wbase) {
#pragma unroll
            for (int jn = 0; jn < 4; ++jn) {
                float4v rf = (float4v)0.f;
#pragma unroll
                for (int kk = 0; kk < 2; ++kk) {
                    int r = jn * 16 + lc;
                    int sw = kk * 4 + rg;
                    short8v bf = *(const short8v*)((const char*)lds_rk + r * 128 + ((sw ^ (r & 7)) << 4));
                    rf = __builtin_amdgcn_mfma_f32_16x16x32_bf16(aqr[kk], bf, rf, 0, 0, 0);
                }
#pragma unroll
                for (int pr = 0; pr < 4; ++pr)
                    rbase[(rg * 4 + pr) * 132 + wbase + jn * 16 + lc] = rf[pr];
            }
        };

        for (int st = st_s; st < st_e; ++st) {
            const int s0 = st * 64;
            const int jb = (st - qt) * 64 + 448;          // window base row (>=0)
            const int sb = ((st - qt + 7) & 1) << 6;      // window base slot

            // ---- stage K, V (every step) ----
#pragma unroll
            for (int i = 0; i < 2; ++i) {
                int rb = w * 16 + i * 8;
                int r  = rb + (lane >> 3);
                int sl = ((lane & 7) ^ (r & 7)) << 3;
                gload16(kb + (long)(s0 + r) * 1024 + sl, lds_k + rb * 64);
                gload16(vtb + (long)r * 512 + s0 + sl, lds_v + rb * 64);
            }
            if (st == st_s) {        // establish full 128-col window
                stage_rk(jb);
                __syncthreads();
                rel_half(sb);
                __syncthreads();
                stage_rk(jb + 64);
                __syncthreads();
            } else {
                stage_rk(jb + 64);   // only the new upper half
                __syncthreads();
            }

            // ---- content scores (16 q-rows x 64 s) ----
            float4v sfr[4];
#pragma unroll
            for (int sn = 0; sn < 4; ++sn) {
                sfr[sn] = (float4v)0.f;
#pragma unroll
                for (int kk = 0; kk < 2; ++kk) {
                    int r = sn * 16 + lc;
                    int sw = kk * 4 + rg;
                    short8v bf = *(const short8v*)((const char*)lds_k + r * 128 + ((sw ^ (r & 7)) << 4));
                    sfr[sn] = __builtin_amdgcn_mfma_f32_16x16x32_bf16(aqw[kk], bf, sfr[sn], 0, 0, 0);
                }
            }
            rel_half(sb ^ 64);       // upper half of current window

            // ---- combine + shift + mask + online softmax ----
            float pv[4][4];
            float rmax[4] = {-3e38f, -3e38f, -3e38f, -3e38f};
#pragma unroll
            for (int pr = 0; pr < 4; ++pr) {
                int tt = rg * 4 + pr;
                int tw = w * 16 + tt;
#pragma unroll
                for (int sn = 0; sn < 4; ++sn) {
                    int ss = sn * 16 + lc;
                    int slot = (sb + ss + 63 - tw) & 127;
                    float lg = (sfr[sn][pr] + rbase[tt * 132 + slot]) * 0.125f;
                    if (ss > t0 - s0 + tw) lg = -1e30f;   // causal
                    pv[sn][pr] = lg;
                    rmax[pr] = fmaxf(rmax[pr], lg);
                }
            }
#pragma unroll
            for (int o = 1; o < 16; o <<= 1)
#pragma unroll
                for (int pr = 0; pr < 4; ++pr)
                    rmax[pr] = fmaxf(rmax[pr], __shfl_xor(rmax[pr], o));
            float rsum[4];
#pragma unroll
            for (int pr = 0; pr < 4; ++pr) {
                float mn = fmaxf(mrow[pr], rmax[pr]);
                float al = __expf(mrow[pr] - mn);
                mrow[pr] = mn;
                lrow[pr] *= al;
                float s = 0.f;
#pragma unroll
                for (int sn = 0; sn < 4; ++sn) {
                    float p = __expf(pv[sn][pr] - mn);
                    pv[sn][pr] = p;
                    s += p;
                }
                rsum[pr] = s;
#pragma unroll
                for (int dn = 0; dn < 4; ++dn) oacc[dn][pr] *= al;
            }
#pragma unroll
            for (int o = 1; o < 16; o <<= 1)
#pragma unroll
                for (int pr = 0; pr < 4; ++pr)
                    rsum[pr] += __shfl_xor(rsum[pr], o);
#pragma unroll
            for (int pr = 0; pr < 4; ++pr) lrow[pr] += rsum[pr];

            // ---- P -> per-wave LDS (bf16, swizzled for A-frag reads) ----
#pragma unroll
            for (int pr = 0; pr < 4; ++pr) {
                int row = rg * 4 + pr;
#pragma unroll
                for (int sn = 0; sn < 4; ++sn) {
                    int col = sn * 16 + lc;
                    *(us*)((char*)pbase + row * 128 + (((col >> 3) ^ (row & 7)) << 4) + (col & 7) * 2)
                        = f2bf(pv[sn][pr]);
                }
            }
            // ---- PV accumulate ----
            short8v pa[2];
#pragma unroll
            for (int kk = 0; kk < 2; ++kk)
                pa[kk] = *(const short8v*)((const char*)pbase + lc * 128 + (((kk * 4 + rg) ^ (lc & 7)) << 4));
#pragma unroll
            for (int dn = 0; dn < 4; ++dn) {
#pragma unroll
                for (int kk = 0; kk < 2; ++kk) {
                    int r = dn * 16 + lc;
                    int sw = kk * 4 + rg;
                    short8v vb = *(const short8v*)((const char*)lds_v + r * 128 + ((sw ^ (r & 7)) << 4));
                    oacc[dn] = __builtin_amdgcn_mfma_f32_16x16x32_bf16(pa[kk], vb, oacc[dn], 0, 0, 0);
                }
            }
            __syncthreads();   // all waves done with lds before next stage
        }

        // ---- store UNNORMALIZED partials (O fp32, m, l) ----
#pragma unroll
        for (int pr = 0; pr < 4; ++pr) {
            int t = t0 + w * 16 + rg * 4 + pr;
            long rowi = (long)(hf * 64 + bh) * 512 + t;
            float* od = pO + rowi * 64;
#pragma unroll
            for (int dn = 0; dn < 4; ++dn)
                od[dn * 16 + lc] = oacc[dn][pr];
            if (lc == 0) { pm[rowi] = mrow[pr]; pl[rowi] = lrow[pr]; }
        }
    }
}

// =====================================================================
// Attention partial merge: O = (a0*O0 + a1*O1) / (a0*l0 + a1*l1),
// a_i = exp(m_i - max(m0,m1)).  Writes bf16 o_bf[b,t,h,d].
// =====================================================================
__global__ __launch_bounds__(256)
void amerge_k(const float* __restrict__ pO, const float* __restrict__ pm,
              const float* __restrict__ pl, us* __restrict__ obuf)
{
    int row = blockIdx.x * 4 + (threadIdx.x >> 6);   // bh*512 + t  (32768 rows)
    int d   = threadIdx.x & 63;
    float m0 = pm[row], m1 = pm[row + 32768];
    float l0 = pl[row], l1 = pl[row + 32768];
    float M  = fmaxf(m0, m1);
    float a0 = __expf(m0 - M), a1 = __expf(m1 - M);
    float L  = a0 * l0 + a1 * l1;
    long i0 = (long)row * 64 + d;
    float o = (a0 * pO[i0] + a1 * pO[i0 + 2097152]) / L;
    int bh = row >> 9, t = row & 511;
    int b = bh >> 4, h = bh & 15;
    obuf[((long)(b * 512 + t)) * 1024 + h * 64 + d] = f2bf(o);
}

// =====================================================================
// Transpose-convert: fp32 in[R][C] -> bf16 out[C][R], optional layer batch
// =====================================================================
__global__ __launch_bounds__(256)
void tconv_k(const float* __restrict__ in, us* __restrict__ out, int R, int C,
             long inL, long outL)
{
    in  += (long)blockIdx.z * inL;
    out += (long)blockIdx.z * outL;
    __shared__ float t[32][33];
    int c0 = blockIdx.x * 32, r0 = blockIdx.y * 32;
    int tx = threadIdx.x & 31, ty = threadIdx.x >> 5;
#pragma unroll
    for (int j = 0; j < 4; ++j)
        t[ty + j * 8][tx] = in[(long)(r0 + ty + j * 8) * C + c0 + tx];
    __syncthreads();
#pragma unroll
    for (int j = 0; j < 4; ++j)
        out[(long)(c0 + ty + j * 8) * R + r0 + tx] = f2bf(t[tx][ty + j * 8]);
}

// all small fp32->bf16 conversions in one launch (block ranges align to
// region boundaries: 2000|1500|1500|256|64 blocks of 1024 floats each)
__global__ __launch_bounds__(256)
void convall_k(const float* __restrict__ e0, const float* __restrict__ e1,
               const float* __restrict__ e2, const float* __restrict__ p1,
               const float* __restrict__ p2,
               us* __restrict__ d0, us* __restrict__ d1, us* __restrict__ d2,
               us* __restrict__ d3, us* __restrict__ d4)
{
    int blk = blockIdx.x;
    const float* s; us* d; long off;
    if (blk < 2000)      { s = e0; d = d0; off = (long)blk * 1024; }
    else if (blk < 3500) { s = e1; d = d1; off = (long)(blk - 2000) * 1024; }
    else if (blk < 5000) { s = e2; d = d2; off = (long)(blk - 3500) * 1024; }
    else if (blk < 5256) { s = p1; d = d3; off = (long)(blk - 5000) * 1024; }
    else                 { s = p2; d = d4; off = (long)(blk - 5256) * 1024; }
    long i = off + (long)threadIdx.x * 4;
    float4 v = *reinterpret_cast<const float4*>(s + i);
    uint2 p;
    p.x = (unsigned)f2bf(v.x) | ((unsigned)f2bf(v.y) << 16);
    p.y = (unsigned)f2bf(v.z) | ((unsigned)f2bf(v.w) << 16);
    *reinterpret_cast<uint2*>(d + i) = p;
}

// zero rk pad rows [512,640) for all 12 layers
__global__ __launch_bounds__(256)
void rkpad12_k(us* __restrict__ rk)
{
    int i = blockIdx.x * 256 + threadIdx.x;   // 98304 uint4 total
    int l = i >> 13, r = i & 8191;
    reinterpret_cast<uint4*>(rk + (long)l * RKL + 512 * 1024)[r] = make_uint4(0, 0, 0, 0);
}

// concat per-layer qkv biases: bqkv[l][3072] = [bq|bk|bv]
__global__ __launch_bounds__(256)
void bcat_k(const float* __restrict__ bq, const float* __restrict__ bk,
            const float* __restrict__ bv, float* __restrict__ o)
{
    int i = blockIdx.x * 256 + threadIdx.x;       // 12*3072
    int l = i / 3072, rr = i % 3072, seg = rr >> 10, c = rr & 1023;
    const float* s = seg == 0 ? bq : seg == 1 ? bk : bv;
    o[i] = s[l * 1024 + c];
}

// =====================================================================
// LayerNorm D=1024 fp32 -> bf16, one block/row (prologue only)
// =====================================================================
__global__ __launch_bounds__(256)
void ln_k(const float* __restrict__ x, us* __restrict__ y,
          const float* __restrict__ sc, const float* __restrict__ bi)
{
    int row = blockIdx.x;
    const float* xr = x + (long)row * ND;
    int d4 = threadIdx.x * 4;
    float4 v = *reinterpret_cast<const float4*>(&xr[d4]);
    float sum = v.x + v.y + v.z + v.w;
    float sq  = v.x * v.x + v.y * v.y + v.z * v.z + v.w * v.w;
#pragma unroll
    for (int o = 32; o; o >>= 1) { sum += __shfl_xor(sum, o); sq += __shfl_xor(sq, o); }
    __shared__ float red[8];
    int w = threadIdx.x >> 6;
    if ((threadIdx.x & 63) == 0) { red[w] = sum; red[4 + w] = sq; }
    __syncthreads();
    sum = red[0] + red[1] + red[2] + red[3];
    sq  = red[4] + red[5] + red[6] + red[7];
    float mean = sum * (1.f / ND);
    float var  = fmaxf(sq * (1.f / ND) - mean * mean, 0.f);
    float inv  = rsqrtf(var + 1e-5f);
    float4 s4 = *reinterpret_cast<const float4*>(&sc[d4]);
    float4 b4 = *reinterpret_cast<const float4*>(&bi[d4]);
    uint2 p;
    p.x = (unsigned)f2bf((v.x - mean) * inv * s4.x + b4.x)
        | ((unsigned)f2bf((v.y - mean) * inv * s4.y + b4.y) << 16);
    p.y = (unsigned)f2bf((v.z - mean) * inv * s4.z + b4.z)
        | ((unsigned)f2bf((v.w - mean) * inv * s4.w + b4.w) << 16);
    *reinterpret_cast<uint2*>(y + (long)row * ND + d4) = p;
}

// sinusoid pos-emb (TXL order), bf16 out
__global__ __launch_bounds__(256)
void pemb_k(us* __restrict__ p)
{
    int t = blockIdx.x;
    float pos = (float)(NT - 1 - t);
    for (int j = threadIdx.x; j < ND / 2; j += 256) {
        float invf = expf(-(float)j * (9.210340371976184f / 512.0f));
        float ang  = pos * invf;
        p[(long)t * ND + j]           = f2bf(sinf(ang));
        p[(long)t * ND + ND / 2 + j]  = f2bf(cosf(ang));
    }
}

// adaptive input embedding -> h fp32
__global__ __launch_bounds__(256)
void embed_k(const int* __restrict__ x,
             const float* __restrict__ e0, const float* __restrict__ e1,
             const float* __restrict__ e2, const float* __restrict__ p1,
             const float* __restrict__ p2, float* __restrict__ h)
{
    __shared__ float e[256];
    int tok = blockIdx.x;
    int v = x[tok];
    float* outp = h + (long)tok * ND;
    if (v < 2000) {
        const float* r = e0 + (long)v * ND;
        for (int d = threadIdx.x; d < ND; d += 256) outp[d] = r[d] * 32.0f;
    } else if (v < 8000) {
        const float* r = e1 + (long)(v - 2000) * 256;
        e[threadIdx.x] = r[threadIdx.x];
        __syncthreads();
        for (int d = threadIdx.x; d < ND; d += 256) {
            float acc = 0.f;
#pragma unroll 4
            for (int i = 0; i < 256; ++i) acc += e[i] * p1[(long)i * ND + d];
            outp[d] = acc * 32.0f;
        }
    } else {
        const float* r = e2 + (long)(v - 8000) * 64;
        if (threadIdx.x < 64) e[threadIdx.x] = r[threadIdx.x];
        __syncthreads();
        for (int d = threadIdx.x; d < ND; d += 256) {
            float acc = 0.f;
#pragma unroll 4
            for (int i = 0; i < 64; ++i) acc += e[i] * p2[(long)i * ND + d];
            outp[d] = acc * 32.0f;
        }
    }
}

// ---------------------------------------------------------------- host
extern "C" void kernel_launch(void* const* d_in, const int* in_sizes, int n_in,
                              void* d_out, int out_size, void* d_ws, size_t ws_size,
                              hipStream_t stream)
{
    (void)in_sizes; (void)n_in; (void)out_size;
    const int*   x     = (const int*)  d_in[0];
    const float* emb0  = (const float*)d_in[1];
    const float* emb1  = (const float*)d_in[2];
    const float* emb2  = (const float*)d_in[3];
    const float* proj1 = (const float*)d_in[4];
    const float* proj2 = (const float*)d_in[5];
    const float* obias = (const float*)d_in[6];
    const float* rwb   = (const float*)d_in[7];
    const float* rrb   = (const float*)d_in[8];
    const float* ln1s  = (const float*)d_in[9];
    const float* ln1b  = (const float*)d_in[10];
    const float* Wq    = (const float*)d_in[11];
    const float* bq    = (const float*)d_in[12];
    const float* Wk    = (const float*)d_in[13];
    const float* bk    = (const float*)d_in[14];
    const float* Wv    = (const float*)d_in[15];
    const float* bv    = (const float*)d_in[16];
    const float* Wr    = (const float*)d_in[17];
    const float* Wo    = (const float*)d_in[18];
    const float* bo    = (const float*)d_in[19];
    const float* ln2s  = (const float*)d_in[20];
    const float* ln2b  = (const float*)d_in[21];
    const float* W1    = (const float*)d_in[22];
    const float* b1    = (const float*)d_in[23];
    const float* W2    = (const float*)d_in[24];
    const float* b2    = (const float*)d_in[25];
    float* out = (float*)d_out;

    // ---- d_out scratch (us-unit offsets); all dead before vocab GEMMs ----
    us* ob      = (us*)out;
    us* qkvbuf  = ob;                 // 6,291,456  (qw|qr|k)
    us* mid_bf  = ob +  6291456;      // 8,388,608  [2048][4096]
    us* vt_bf   = ob + 14680064;      // 2,097,152  [64][64][512]
    us* o_bf    = ob + 16777216;      // 2,097,152  [2048][1024]
    us* ain_bf  = ob + 18874368;      // 2,097,152  [2048][1024]
    us* rk_all  = ob + 20971520;      // 7,864,320  [12][640][1024] (pad rows zero)
    us* pemb_bf = ob + 28835840;      //   524,288  [512][1024]
    // fallback per-layer weight scratch (only used if ws too small)
    us* wqkv_sc = ob + 29360128;      // 3,145,728
    us* wr_sc   = ob + 32505856;      // 1,048,576
    us* wo_sc   = ob + 33554432;      // 1,048,576
    us* w1_sc   = ob + 34603008;      // 4,194,304
    us* w2_sc   = ob + 38797312;      // 4,194,304  (ends 42,991,616 us)
    float* pffn = out + 21495808;     // 8,388,608 f: [4][2048][1024] fp32 partials
    float* pwo  = out + 29884416;     // 4,194,304 f: [2][2048][1024] fp32 partials
    float* pO   = out + 34078720;     // 8,388,608 f: [2][64][512][64] attn partials
    float* pm   = out + 42467328;     //    65,536 f: [2][64*512]
    float* pl   = out + 42532864;     //    65,536 f  (ends 42,598,400 f)

    // ---- d_ws layout ----
    float* wsf      = (float*)d_ws;
    float* h        = wsf;                         // 2,097,152 f
    us*    h_bf     = (us*)(wsf + 2097152);
    us*    hp1_bf   = h_bf   + 2097152;            // 524,288
    us*    hp2_bf   = hp1_bf + 524288;             // 131,072
    us*    emb0_bf  = hp2_bf + 131072;             // 2048x1024 (2000 real)
    us*    emb1_bf  = emb0_bf + 2097152;           // 6144x256  (6000 real)
    us*    emb2_bf  = emb1_bf + 1572864;           // 24064x64  (24000 real)
    us*    proj1_bf = emb2_bf + 1540096;           // 256x1024
    us*    proj2_bf = proj1_bf + 262144;           // 64x1024
    float* bqkv     = (float*)(proj2_bf + 65536);  // 12*3072 f
    us*    wqkv_all = (us*)(bqkv + 36864);         // [12][3072][1024]
    us*    wr_all   = wqkv_all + (long)NL * 3072 * 1024;
    us*    wo_all   = wr_all   + (long)NL * 1024 * 1024;
    us*    w1_all   = wo_all   + (long)NL * 1024 * 1024;   // [12][4096][1024]
    us*    w2_all   = w1_all   + (long)NL * 4096 * 1024;   // [12][1024][4096]
    const bool big  = ws_size >= (size_t)352273408;        // full weight cache fits

    // ---- one-time setup ----
    bcat_k<<<144, 256, 0, stream>>>(bq, bk, bv, bqkv);
    convall_k<<<5320, 256, 0, stream>>>(emb0, emb1, emb2, proj1, proj2,
                                        emb0_bf, emb1_bf, emb2_bf, proj1_bf, proj2_bf);
    pemb_k<<<NT, 256, 0, stream>>>(pemb_bf);
    rkpad12_k<<<384, 256, 0, stream>>>(rk_all);
    embed_k<<<NBT, 256, 0, stream>>>(x, emb0, emb1, emb2, proj1, proj2, h);
    if (big) {   // batched all-layer weight transpose-convert (7 launches)
        tconv_k<<<dim3(32, 32, NL), 256, 0, stream>>>(Wq, wqkv_all,           1024, 1024, 1048576, 3145728);
        tconv_k<<<dim3(32, 32, NL), 256, 0, stream>>>(Wk, wqkv_all + 1048576, 1024, 1024, 1048576, 3145728);
        tconv_k<<<dim3(32, 32, NL), 256, 0, stream>>>(Wv, wqkv_all + 2097152, 1024, 1024, 1048576, 3145728);
        tconv_k<<<dim3(32, 32, NL), 256, 0, stream>>>(Wr, wr_all, 1024, 1024, 1048576, 1048576);
        tconv_k<<<dim3(32, 32, NL), 256, 0, stream>>>(Wo, wo_all, 1024, 1024, 1048576, 1048576);
        tconv_k<<<dim3(128, 32, NL), 256, 0, stream>>>(W1, w1_all, 1024, 4096, 4194304, 4194304);
        tconv_k<<<dim3(32, 128, NL), 256, 0, stream>>>(W2, w2_all, 4096, 1024, 4194304, 4194304);
        // batched r_k for all layers: rk_all[l] = pemb @ Wr[l]
        bgemm_k<64, 64, 0, true><<<dim3(16, 8, NL), 256, 0, stream>>>(
            pemb_bf, wr_all, rk_all, nullptr, nullptr, nullptr, nullptr, nullptr,
            1024, 1024, 1024, 1024, 1024,
            1, 0, 0, 1048576, 0, RKL, 0);
    }
    // prologue: ln1 of layer 0
    ln_k<<<NBT, 256, 0, stream>>>(h, ain_bf, ln1s, ln1b);

    for (int l = 0; l < NL; ++l) {
        const us* wqkv_t = big ? wqkv_all + (long)l * 3145728 : wqkv_sc;
        const us* wo_t   = big ? wo_all   + (long)l * 1048576 : wo_sc;
        const us* w1_t   = big ? w1_all   + (long)l * 4194304 : w1_sc;
        const us* w2_t   = big ? w2_all   + (long)l * 4194304 : w2_sc;
        if (!big) {
            const long wOff = (long)l * ND * ND;
            tconv_k<<<dim3(32, 32), 256, 0, stream>>>(Wq + wOff, wqkv_sc,           1024, 1024, 0, 0);
            tconv_k<<<dim3(32, 32), 256, 0, stream>>>(Wk + wOff, wqkv_sc + 1048576, 1024, 1024, 0, 0);
            tconv_k<<<dim3(32, 32), 256, 0, stream>>>(Wv + wOff, wqkv_sc + 2097152, 1024, 1024, 0, 0);
            tconv_k<<<dim3(32, 32), 256, 0, stream>>>(Wr + wOff, wr_sc, 1024, 1024, 0, 0);
            tconv_k<<<dim3(32, 32), 256, 0, stream>>>(Wo + wOff, wo_sc, 1024, 1024, 0, 0);
            tconv_k<<<dim3(128, 32), 256, 0, stream>>>(W1 + (long)l * ND * NF, w1_sc, 1024, 4096, 0, 0);
            tconv_k<<<dim3(32, 128), 256, 0, stream>>>(W2 + (long)l * ND * NF, w2_sc, 4096, 1024, 0, 0);
            bgemm_k<64, 64, 0, true><<<dim3(16, 8, 1), 256, 0, stream>>>(
                pemb_bf, wr_sc, rk_all + (long)l * RKL, nullptr, nullptr, nullptr, nullptr, nullptr,
                1024, 1024, 1024, 1024, 1024, 0, 0, 0, 0, 0, 0, 0);
        }

        // fused QKV (EPI=3): qw,qr,k into qkvbuf; v straight into vt
        bgemm_k<128, 64, 3, true><<<dim3(48, 16, 1), 256, 0, stream>>>(
            ain_bf, wqkv_t, qkvbuf, bqkv + l * 3072, nullptr, rwb, rrb, vt_bf,
            3072, 1024, 1024, 1024, 1024, 0, 0, 0, 0, 0, 0, 0);
        // fused attention, 2-way kv split -> partials, then merge
        fattn_k<<<dim3(4, NB * NH, 2), 256, 0, stream>>>(
            qkvbuf, vt_bf, rk_all + (long)l * RKL, pO, pm, pl);
        amerge_k<<<8192, 256, 0, stream>>>(pO, pm, pl, o_bf);
        // Wo split-K=2 at 128x64 tiles -> fp32 partials
        bgemm_k<128, 64, 0, false><<<dim3(16, 16, 2), 256, 0, stream>>>(
            o_bf, wo_t, pwo, nullptr, nullptr, nullptr, nullptr, nullptr,
            1024, 512, 1024, 1024, 1024,
            1, 512, 0, 512, 0, 2097152, 0);
        // h += bo + sum(pwo); ain = LN2(h)
        redln_k<2, 0><<<NBT, 256, 0, stream>>>(
            pwo, bo + l * ND, h, ain_bf, ln2s + l * ND, ln2b + l * ND);

        // FFN
        bgemm_k<128, 128, 1, true><<<dim3(32, 16, 1), 256, 0, stream>>>(
            ain_bf, w1_t, mid_bf, b1 + (long)l * NF, nullptr, nullptr, nullptr, nullptr,
            4096, 1024, 1024, 1024, 4096, 0, 0, 0, 0, 0, 0, 0);
        // FFN2 split-K=4 at 128x128 tiles -> fp32 partials
        bgemm_k<128, 128, 0, false><<<dim3(8, 16, 4), 256, 0, stream>>>(
            mid_bf, w2_t, pffn, nullptr, nullptr, nullptr, nullptr, nullptr,
            1024, 1024, 4096, 4096, 1024,
            1, 1024, 0, 1024, 0, 2097152, 0);
        // h += b2 + sum(pffn); then LN1(next layer) or bf16 convert (last)
        if (l < NL - 1)
            redln_k<4, 0><<<NBT, 256, 0, stream>>>(
                pffn, b2 + (long)l * ND, h, ain_bf,
                ln1s + (l + 1) * ND, ln1b + (l + 1) * ND);
        else
            redln_k<4, 1><<<NBT, 256, 0, stream>>>(
                pffn, b2 + (long)l * ND, h, h_bf, nullptr, nullptr);
    }

    // ---- tied adaptive-softmax output: (h @ proj^T) @ emb^T ----
    // cluster 0: cols [0,2000)
    bgemm_k<128, 64, 0, false><<<dim3(32, 16, 1), 256, 0, stream>>>(
        h_bf, emb0_bf, out, obias, nullptr, nullptr, nullptr, nullptr,
        2000, 1024, 1024, 1024, NV, 0, 0, 0, 0, 0, 0, 0);
    // cluster 1: hp1 = h @ proj1^T ; cols [2000,8000)
    bgemm_k<64, 64, 0, true><<<dim3(4, 32, 1), 256, 0, stream>>>(
        h_bf, proj1_bf, hp1_bf, nullptr, nullptr, nullptr, nullptr, nullptr,
        256, 1024, 1024, 1024, 256, 0, 0, 0, 0, 0, 0, 0);
    bgemm_k<128, 128, 0, false><<<dim3(47, 16, 1), 256, 0, stream>>>(
        hp1_bf, emb1_bf, out + 2000, obias + 2000, nullptr, nullptr, nullptr, nullptr,
        6000, 256, 256, 256, NV, 0, 0, 0, 0, 0, 0, 0);
    // cluster 2: hp2 = h @ proj2^T ; cols [8000,32000)
    bgemm_k<64, 64, 0, true><<<dim3(1, 32, 1), 256, 0, stream>>>(
        h_bf, proj2_bf, hp2_bf, nullptr, nullptr, nullptr, nullptr, nullptr,
        64, 1024, 1024, 1024, 64, 0, 0, 0, 0, 0, 0, 0);
    bgemm_k<128, 128, 0, false><<<dim3(188, 16, 1), 256, 0, stream>>>(
        hp2_bf, emb2_bf, out + 8000, obias + 8000, nullptr, nullptr, nullptr, nullptr,
        24000, 64, 64, 64, NV, 0, 0, 0, 0, 0, 0, 0);
}

// Round 13
// 2451.556 us; speedup vs baseline: 1.0055x; 1.0055x over previous
//
#include <hip/hip_runtime.h>

using us = unsigned short;
typedef short short8v __attribute__((ext_vector_type(8)));
typedef float float4v __attribute__((ext_vector_type(4)));

// ---------------- problem constants ----------------
constexpr int NB  = 4;
constexpr int NT  = 512;
constexpr int ND  = 1024;
constexpr int NL  = 12;
constexpr int NH  = 16;
constexpr int NF  = 4096;
constexpr int NHD = 64;
constexpr int NBT = NB * NT;   // 2048
constexpr int NV  = 32000;
constexpr long QOFF = (long)NBT * ND;  // qw|qr|k stride in qkvbuf
constexpr long RKL  = 640L * 1024;     // per-layer rk stride (rows 512.. are zero pad)

__device__ __forceinline__ us f2bf(float f) {
    unsigned u = __float_as_uint(f);
    u += 0x7fffu + ((u >> 16) & 1u);      // RNE
    return (us)(u >> 16);
}

// async global->LDS, 16B per lane. LDS dest is wave-uniform base + lane*16;
// global src is per-lane (pre-swizzled for bank-conflict-free ds_read).
__device__ __forceinline__ void gload16(const us* g, us* l) {
    __builtin_amdgcn_global_load_lds(
        (const __attribute__((address_space(1))) void*)g,
        (__attribute__((address_space(3))) void*)l, 16, 0, 0);
}

// =====================================================================
// bf16 MFMA GEMM:  C[M,N] = A[M,K] @ B[N,K]^T   (both row-major, k-contig)
// 256 threads = 4 waves (2x2), per-wave tile (BM/2)x(BN/2), BK=64.
// TWO-PHASE double-buffered staging (prefetch next tile under MFMA).
// EPI: 0 plain (+bias,+addsrc), 1 gelu, 3 fused QKV epilogue:
//      seg0 -> qw,qr (+r_w/r_r bias), seg1 -> k, seg2 -> vt[b,h,d,t] packed.
// =====================================================================
template<int BM, int BN, int EPI, bool OUTBF>
__global__ __launch_bounds__(256)
void bgemm_k(const us* __restrict__ A, const us* __restrict__ B, void* Cv,
             const float* __restrict__ bias, const float* addsrc,
             const float* __restrict__ p0, const float* __restrict__ p1,
             us* __restrict__ vtp,
             int N, int K, int lda, int ldb, int ldc,
             int bdiv, long sAb, long sAh, long sBb, long sBh, long sCb, long sCh)
{
    constexpr int BK  = 64;
    constexpr int WTM = BM / 2, WTN = BN / 2;
    constexpr int FM  = WTM / 16, FN = WTN / 16;
    constexpr int AI  = BM / 32;       // gload16 instr per wave (A tile)
    constexpr int BI  = BN / 32;
    static_assert(BM % 32 == 0 && BN % 32 == 0, "");

    long coff = 0;
    if (bdiv > 0) {
        int z = blockIdx.z, zb = z / bdiv, zh = z % bdiv;
        A += zb * sAb + zh * sAh;
        B += zb * sBb + zh * sBh;
        coff = zb * sCb + zh * sCh;
    }
    float* Cf = (float*)Cv + coff;
    us*    Ch = (us*)Cv + coff;
    if (addsrc) addsrc += coff;

    __shared__ __align__(16) us As[2 * BM * BK];
    __shared__ __align__(16) us Bs[2 * BN * BK];

    const int tid  = threadIdx.x;
    const int lane = tid & 63;
    const int w    = tid >> 6;
    const int wm   = w >> 1;
    const int wn   = w & 1;
    const int row0 = blockIdx.y * BM;
    const int col0 = blockIdx.x * BN;

    float4v acc[FM][FN];
#pragma unroll
    for (int i = 0; i < FM; ++i)
#pragma unroll
        for (int j = 0; j < FN; ++j) acc[i][j] = (float4v)0.f;

    auto stage = [&](int buf, int k0) {
        us* Ad = As + buf * (BM * BK);
        us* Bd = Bs + buf * (BN * BK);
#pragma unroll
        for (int i = 0; i < AI; ++i) {
            int rb = w * (BM / 4) + i * 8;
            int r  = rb + (lane >> 3);
            int sc8 = ((lane & 7) ^ (r & 7)) << 3;
            gload16(A + (long)(row0 + r) * lda + k0 + sc8, Ad + rb * 64);
        }
#pragma unroll
        for (int i = 0; i < BI; ++i) {
            int rb = w * (BN / 4) + i * 8;
            int r  = rb + (lane >> 3);
            int sc8 = ((lane & 7) ^ (r & 7)) << 3;
            gload16(B + (long)(col0 + r) * ldb + k0 + sc8, Bd + rb * 64);
        }
    };

    stage(0, 0);
    __syncthreads();           // buf0 staged (vmcnt drained)
    int cur = 0;
    for (int k0 = 0; k0 < K; k0 += BK) {
        if (k0 + BK < K) stage(cur ^ 1, k0 + BK);   // prefetch next tile
        const char* Ac = (const char*)(As + cur * (BM * BK));
        const char* Bc = (const char*)(Bs + cur * (BN * BK));
#pragma unroll
        for (int ks = 0; ks < 2; ++ks) {
            short8v af[FM], bfr[FN];
            int sw = ks * 4 + (lane >> 4);
#pragma unroll
            for (int i = 0; i < FM; ++i) {
                int r = wm * WTM + i * 16 + (lane & 15);
                af[i] = *reinterpret_cast<const short8v*>(Ac + r * 128 + ((sw ^ (r & 7)) << 4));
            }
#pragma unroll
            for (int j = 0; j < FN; ++j) {
                int r = wn * WTN + j * 16 + (lane & 15);
                bfr[j] = *reinterpret_cast<const short8v*>(Bc + r * 128 + ((sw ^ (r & 7)) << 4));
            }
#pragma unroll
            for (int i = 0; i < FM; ++i)
#pragma unroll
                for (int j = 0; j < FN; ++j)
                    acc[i][j] = __builtin_amdgcn_mfma_f32_16x16x32_bf16(af[i], bfr[j], acc[i][j], 0, 0, 0);
        }
        __syncthreads();       // next tile staged; all waves done reading cur
        cur ^= 1;
    }

    // ---- epilogue.  D layout: col = lane&15, row = (lane>>4)*4 + reg ----
#pragma unroll
    for (int i = 0; i < FM; ++i) {
        int growb = row0 + wm * WTM + i * 16 + ((lane >> 4) << 2);
#pragma unroll
        for (int j = 0; j < FN; ++j) {
            int gcol = col0 + wn * WTN + j * 16 + (lane & 15);
            if (EPI == 3) {
                int seg = gcol >> 10, c = gcol & 1023;
                float bb = bias[gcol];
                if (seg == 2) {
                    // v -> vt[b,h,d,t], 4 consecutive t packed into 8B
                    unsigned lo = (unsigned)f2bf(acc[i][j][0] + bb)
                                | ((unsigned)f2bf(acc[i][j][1] + bb) << 16);
                    unsigned hi = (unsigned)f2bf(acc[i][j][2] + bb)
                                | ((unsigned)f2bf(acc[i][j][3] + bb) << 16);
                    int bidx = growb >> 9, tb = growb & 511;
                    uint2 pk; pk.x = lo; pk.y = hi;
                    *reinterpret_cast<uint2*>(
                        vtp + ((long)((bidx * 16 + (c >> 6)) * 64 + (c & 63)) << 9) + tb) = pk;
                } else {
                    us* base = (us*)Cv;
#pragma unroll
                    for (int r = 0; r < 4; ++r) {
                        int gr = growb + r;
                        float v = acc[i][j][r] + bb;
                        long o = (long)gr * 1024 + c;
                        if (seg == 0) {
                            base[o]        = f2bf(v + p0[c]);   // qw
                            base[o + QOFF] = f2bf(v + p1[c]);   // qr
                        } else base[o + 2 * QOFF] = f2bf(v);    // k
                    }
                }
            } else {
                if (gcol >= N) continue;
#pragma unroll
                for (int r = 0; r < 4; ++r) {
                    int gr = growb + r;
                    float v = acc[i][j][r];
                    if (bias) v += bias[gcol];
                    if (EPI == 1) {
                        float xx = v;
                        v = 0.5f * xx * (1.f + tanhf(0.7978845608028654f
                                                     * (xx + 0.044715f * xx * xx * xx)));
                    }
                    if (addsrc) v += addsrc[(long)gr * ldc + gcol];
                    if (OUTBF) Ch[(long)gr * ldc + gcol] = f2bf(v);
                    else       Cf[(long)gr * ldc + gcol] = v;
                }
            }
        }
    }
}

// =====================================================================
// Fused split-K reduce + residual + (LN -> bf16 | bf16 convert).
// =====================================================================
template<int NPART, int MODE>
__global__ __launch_bounds__(256)
void redln_k(const float* __restrict__ part, const float* __restrict__ bias,
             float* __restrict__ h, us* __restrict__ outb,
             const float* __restrict__ sc, const float* __restrict__ bi)
{
    int row = blockIdx.x;
    int d4 = threadIdx.x * 4;
    long i = (long)row * ND + d4;
    float4 hv = *reinterpret_cast<const float4*>(h + i);
    float4 bb = *reinterpret_cast<const float4*>(bias + d4);
    hv.x += bb.x; hv.y += bb.y; hv.z += bb.z; hv.w += bb.w;
#pragma unroll
    for (int z = 0; z < NPART; ++z) {
        float4 a = *reinterpret_cast<const float4*>(part + (long)z * 2097152 + i);
        hv.x += a.x; hv.y += a.y; hv.z += a.z; hv.w += a.w;
    }
    *reinterpret_cast<float4*>(h + i) = hv;
    if (MODE == 1) {
        uint2 p;
        p.x = (unsigned)f2bf(hv.x) | ((unsigned)f2bf(hv.y) << 16);
        p.y = (unsigned)f2bf(hv.z) | ((unsigned)f2bf(hv.w) << 16);
        *reinterpret_cast<uint2*>(outb + i) = p;
    } else {
        float sum = hv.x + hv.y + hv.z + hv.w;
        float sq  = hv.x * hv.x + hv.y * hv.y + hv.z * hv.z + hv.w * hv.w;
#pragma unroll
        for (int o = 32; o; o >>= 1) { sum += __shfl_xor(sum, o); sq += __shfl_xor(sq, o); }
        __shared__ float red[8];
        int w = threadIdx.x >> 6;
        if ((threadIdx.x & 63) == 0) { red[w] = sum; red[4 + w] = sq; }
        __syncthreads();
        sum = red[0] + red[1] + red[2] + red[3];
        sq  = red[4] + red[5] + red[6] + red[7];
        float mean = sum * (1.f / ND);
        float var  = fmaxf(sq * (1.f / ND) - mean * mean, 0.f);
        float inv  = rsqrtf(var + 1e-5f);
        float4 s4 = *reinterpret_cast<const float4*>(&sc[d4]);
        float4 b4 = *reinterpret_cast<const float4*>(&bi[d4]);
        uint2 p;
        p.x = (unsigned)f2bf((hv.x - mean) * inv * s4.x + b4.x)
            | ((unsigned)f2bf((hv.y - mean) * inv * s4.y + b4.y) << 16);
        p.y = (unsigned)f2bf((hv.z - mean) * inv * s4.z + b4.z)
            | ((unsigned)f2bf((hv.w - mean) * inv * s4.w + b4.w) << 16);
        *reinterpret_cast<uint2*>(outb + i) = p;
    }
}

// =====================================================================
// Fused TXL attention, ROLLING rel band, LOAD-BALANCED q-tile pairing:
// block (qtp, bh) processes q-tiles qtp and 7-qtp sequentially (both
// halves together = 9 kv-steps for every block -> even makespan).
// (round-9 known-good structure; r10 pipelining and r11 kv-split both
//  measured null -> reverted to the simplest passing variant)
// =====================================================================
__global__ __launch_bounds__(256)
void fattn_k(const us* __restrict__ qkv, const us* __restrict__ vt,
             const us* __restrict__ rk, us* __restrict__ obuf)
{
    __shared__ __align__(16) us lds_k[64 * 64];
    __shared__ __align__(16) us lds_v[64 * 64];
    __shared__ __align__(16) us lds_rk[64 * 64];
    __shared__ __align__(16) us lds_p[4 * 16 * 64];
    __shared__ float lds_r[4 * 16 * 132];       // per-wave R, row stride 132

    const int tid = threadIdx.x, lane = tid & 63, w = tid >> 6;
    const int qtp = blockIdx.x, bh = blockIdx.y;
    const int b = bh >> 4, h = bh & 15;
    const int rg = lane >> 4, lc = lane & 15;

    const us* qwb = qkv + ((long)b * 512) * 1024 + h * 64;   // row stride 1024
    const us* qrb = qwb + QOFF;
    const us* kb  = qwb + 2 * QOFF;
    const us* vtb = vt + (long)bh * 64 * 512;                // rows d, stride 512
    const us* rkb = rk + h * 64;                             // rows j, stride 1024

    float* rbase = lds_r + w * (16 * 132);
    us*    pbase = lds_p + w * (16 * 64);

    for (int hh = 0; hh < 2; ++hh) {
        const int qt = hh ? 7 - qtp : qtp;
        const int t0 = qt * 64;

        // Q fragments (rows t0 + w*16 + lc, k-slices kk*32 + rg*8)
        short8v aqw[2], aqr[2];
        {
            long qrow = (long)(t0 + w * 16 + lc) * 1024;
            int ko = rg * 8;
            aqw[0] = *(const short8v*)(qwb + qrow + ko);
            aqw[1] = *(const short8v*)(qwb + qrow + 32 + ko);
            aqr[0] = *(const short8v*)(qrb + qrow + ko);
            aqr[1] = *(const short8v*)(qrb + qrow + 32 + ko);
        }

        float4v oacc[4];
#pragma unroll
        for (int i = 0; i < 4; ++i) oacc[i] = (float4v)0.f;
        float mrow[4] = {-3e38f, -3e38f, -3e38f, -3e38f};
        float lrow[4] = {0.f, 0.f, 0.f, 0.f};

        // stage one 64-row rk half starting at global row j0
        auto stage_rk = [&](int j0) {
#pragma unroll
            for (int i = 0; i < 2; ++i) {
                int rb = w * 16 + i * 8;
                int r  = rb + (lane >> 3);
                int sl = ((lane & 7) ^ (r & 7)) << 3;
                gload16(rkb + (long)(j0 + r) * 1024 + sl, lds_rk + rb * 64);
            }
        };
        // rel MFMA over the staged 64 rows -> R slots [wbase, wbase+64)
        auto rel_half = [&](int wbase) {
#pragma unroll
            for (int jn = 0; jn < 4; ++jn) {
                float4v rf = (float4v)0.f;
#pragma unroll
                for (int kk = 0; kk < 2; ++kk) {
                    int r = jn * 16 + lc;
                    int sw = kk * 4 + rg;
                    short8v bf = *(const short8v*)((const char*)lds_rk + r * 128 + ((sw ^ (r & 7)) << 4));
                    rf = __builtin_amdgcn_mfma_f32_16x16x32_bf16(aqr[kk], bf, rf, 0, 0, 0);
                }
#pragma unroll
                for (int pr = 0; pr < 4; ++pr)
                    rbase[(rg * 4 + pr) * 132 + wbase + jn * 16 + lc] = rf[pr];
            }
        };

        const int nst = qt + 1;
        for (int st = 0; st < nst; ++st) {
            const int s0 = st * 64;
            const int jb = (st - qt) * 64 + 448;          // window base row (>=0)
            const int sb = ((st - qt + 7) & 1) << 6;      // window base slot

            // ---- stage K, V (every step) ----
#pragma unroll
            for (int i = 0; i < 2; ++i) {
                int rb = w * 16 + i * 8;
                int r  = rb + (lane >> 3);
                int sl = ((lane & 7) ^ (r & 7)) << 3;
                gload16(kb + (long)(s0 + r) * 1024 + sl, lds_k + rb * 64);
                gload16(vtb + (long)r * 512 + s0 + sl, lds_v + rb * 64);
            }
            if (st == 0) {
                stage_rk(jb);            // lower half
                __syncthreads();
                rel_half(sb);
                __syncthreads();         // all waves done with lds_rk
                stage_rk(jb + 64);       // upper half
                __syncthreads();
            } else {
                stage_rk(jb + 64);       // only the new upper half
                __syncthreads();
            }

            // ---- content scores (16 q-rows x 64 s) ----
            float4v sfr[4];
#pragma unroll
            for (int sn = 0; sn < 4; ++sn) {
                sfr[sn] = (float4v)0.f;
#pragma unroll
                for (int kk = 0; kk < 2; ++kk) {
                    int r = sn * 16 + lc;
                    int sw = kk * 4 + rg;
                    short8v bf = *(const short8v*)((const char*)lds_k + r * 128 + ((sw ^ (r & 7)) << 4));
                    sfr[sn] = __builtin_amdgcn_mfma_f32_16x16x32_bf16(aqw[kk], bf, sfr[sn], 0, 0, 0);
                }
            }
            rel_half(sb ^ 64);           // upper half of current window

            // ---- combine + shift + mask + online softmax ----
            float pv[4][4];
            float rmax[4] = {-3e38f, -3e38f, -3e38f, -3e38f};
#pragma unroll
            for (int pr = 0; pr < 4; ++pr) {
                int tt = rg * 4 + pr;
                int tw = w * 16 + tt;
#pragma unroll
                for (int sn = 0; sn < 4; ++sn) {
                    int ss = sn * 16 + lc;
                    int slot = (sb + ss + 63 - tw) & 127;
                    float lg = (sfr[sn][pr] + rbase[tt * 132 + slot]) * 0.125f;
                    if (ss > t0 - s0 + tw) lg = -1e30f;   // causal
                    pv[sn][pr] = lg;
                    rmax[pr] = fmaxf(rmax[pr], lg);
                }
            }
#pragma unroll
            for (int o = 1; o < 16; o <<= 1)
#pragma unroll
                for (int pr = 0; pr < 4; ++pr)
                    rmax[pr] = fmaxf(rmax[pr], __shfl_xor(rmax[pr], o));
            float rsum[4];
#pragma unroll
            for (int pr = 0; pr < 4; ++pr) {
                float mn = fmaxf(mrow[pr], rmax[pr]);
                float al = __expf(mrow[pr] - mn);
                mrow[pr] = mn;
                lrow[pr] *= al;
                float s = 0.f;
#pragma unroll
                for (int sn = 0; sn < 4; ++sn) {
                    float p = __expf(pv[sn][pr] - mn);
                    pv[sn][pr] = p;
                    s += p;
                }
                rsum[pr] = s;
#pragma unroll
                for (int dn = 0; dn < 4; ++dn) oacc[dn][pr] *= al;
            }
#pragma unroll
            for (int o = 1; o < 16; o <<= 1)
#pragma unroll
                for (int pr = 0; pr < 4; ++pr)
                    rsum[pr] += __shfl_xor(rsum[pr], o);
#pragma unroll
            for (int pr = 0; pr < 4; ++pr) lrow[pr] += rsum[pr];

            // ---- P -> per-wave LDS (bf16, swizzled for A-frag reads) ----
#pragma unroll
            for (int pr = 0; pr < 4; ++pr) {
                int row = rg * 4 + pr;
#pragma unroll
                for (int sn = 0; sn < 4; ++sn) {
                    int col = sn * 16 + lc;
                    *(us*)((char*)pbase + row * 128 + (((col >> 3) ^ (row & 7)) << 4) + (col & 7) * 2)
                        = f2bf(pv[sn][pr]);
                }
            }
            // ---- PV accumulate ----
            short8v pa[2];
#pragma unroll
            for (int kk = 0; kk < 2; ++kk)
                pa[kk] = *(const short8v*)((const char*)pbase + lc * 128 + (((kk * 4 + rg) ^ (lc & 7)) << 4));
#pragma unroll
            for (int dn = 0; dn < 4; ++dn) {
#pragma unroll
                for (int kk = 0; kk < 2; ++kk) {
                    int r = dn * 16 + lc;
                    int sw = kk * 4 + rg;
                    short8v vb = *(const short8v*)((const char*)lds_v + r * 128 + ((sw ^ (r & 7)) << 4));
                    oacc[dn] = __builtin_amdgcn_mfma_f32_16x16x32_bf16(pa[kk], vb, oacc[dn], 0, 0, 0);
                }
            }
            __syncthreads();   // all waves done with lds_k/v/rk before next stage
        }
        // ---- normalize + store (regs only; safe before next half stages) ----
#pragma unroll
        for (int pr = 0; pr < 4; ++pr) {
            int t = t0 + w * 16 + rg * 4 + pr;
            float inv = 1.f / lrow[pr];
            long rowo = ((long)b * 512 + t) * 1024 + h * 64;
#pragma unroll
            for (int dn = 0; dn < 4; ++dn)
                obuf[rowo + dn * 16 + lc] = f2bf(oacc[dn][pr] * inv);
        }
    }
}

// =====================================================================
// Transpose-convert: fp32 in[R][C] -> bf16 out[C][R], optional layer batch
// =====================================================================
__global__ __launch_bounds__(256)
void tconv_k(const float* __restrict__ in, us* __restrict__ out, int R, int C,
             long inL, long outL)
{
    in  += (long)blockIdx.z * inL;
    out += (long)blockIdx.z * outL;
    __shared__ float t[32][33];
    int c0 = blockIdx.x * 32, r0 = blockIdx.y * 32;
    int tx = threadIdx.x & 31, ty = threadIdx.x >> 5;
#pragma unroll
    for (int j = 0; j < 4; ++j)
        t[ty + j * 8][tx] = in[(long)(r0 + ty + j * 8) * C + c0 + tx];
    __syncthreads();
#pragma unroll
    for (int j = 0; j < 4; ++j)
        out[(long)(c0 + ty + j * 8) * R + r0 + tx] = f2bf(t[tx][ty + j * 8]);
}

// all small fp32->bf16 conversions in one launch (block ranges align to
// region boundaries: 2000|1500|1500|256|64 blocks of 1024 floats each)
__global__ __launch_bounds__(256)
void convall_k(const float* __restrict__ e0, const float* __restrict__ e1,
               const float* __restrict__ e2, const float* __restrict__ p1,
               const float* __restrict__ p2,
               us* __restrict__ d0, us* __restrict__ d1, us* __restrict__ d2,
               us* __restrict__ d3, us* __restrict__ d4)
{
    int blk = blockIdx.x;
    const float* s; us* d; long off;
    if (blk < 2000)      { s = e0; d = d0; off = (long)blk * 1024; }
    else if (blk < 3500) { s = e1; d = d1; off = (long)(blk - 2000) * 1024; }
    else if (blk < 5000) { s = e2; d = d2; off = (long)(blk - 3500) * 1024; }
    else if (blk < 5256) { s = p1; d = d3; off = (long)(blk - 5000) * 1024; }
    else                 { s = p2; d = d4; off = (long)(blk - 5256) * 1024; }
    long i = off + (long)threadIdx.x * 4;
    float4 v = *reinterpret_cast<const float4*>(s + i);
    uint2 p;
    p.x = (unsigned)f2bf(v.x) | ((unsigned)f2bf(v.y) << 16);
    p.y = (unsigned)f2bf(v.z) | ((unsigned)f2bf(v.w) << 16);
    *reinterpret_cast<uint2*>(d + i) = p;
}

// zero rk pad rows [512,640) for all 12 layers
__global__ __launch_bounds__(256)
void rkpad12_k(us* __restrict__ rk)
{
    int i = blockIdx.x * 256 + threadIdx.x;   // 98304 uint4 total
    int l = i >> 13, r = i & 8191;
    reinterpret_cast<uint4*>(rk + (long)l * RKL + 512 * 1024)[r] = make_uint4(0, 0, 0, 0);
}

// concat per-layer qkv biases: bqkv[l][3072] = [bq|bk|bv]
__global__ __launch_bounds__(256)
void bcat_k(const float* __restrict__ bq, const float* __restrict__ bk,
            const float* __restrict__ bv, float* __restrict__ o)
{
    int i = blockIdx.x * 256 + threadIdx.x;       // 12*3072
    int l = i / 3072, rr = i % 3072, seg = rr >> 10, c = rr & 1023;
    const float* s = seg == 0 ? bq : seg == 1 ? bk : bv;
    o[i] = s[l * 1024 + c];
}

// =====================================================================
// LayerNorm D=1024 fp32 -> bf16, one block/row (prologue only)
// =====================================================================
__global__ __launch_bounds__(256)
void ln_k(const float* __restrict__ x, us* __restrict__ y,
          const float* __restrict__ sc, const float* __restrict__ bi)
{
    int row = blockIdx.x;
    const float* xr = x + (long)row * ND;
    int d4 = threadIdx.x * 4;
    float4 v = *reinterpret_cast<const float4*>(&xr[d4]);
    float sum = v.x + v.y + v.z + v.w;
    float sq  = v.x * v.x + v.y * v.y + v.z * v.z + v.w * v.w;
#pragma unroll
    for (int o = 32; o; o >>= 1) { sum += __shfl_xor(sum, o); sq += __shfl_xor(sq, o); }
    __shared__ float red[8];
    int w = threadIdx.x >> 6;
    if ((threadIdx.x & 63) == 0) { red[w] = sum; red[4 + w] = sq; }
    __syncthreads();
    sum = red[0] + red[1] + red[2] + red[3];
    sq  = red[4] + red[5] + red[6] + red[7];
    float mean = sum * (1.f / ND);
    float var  = fmaxf(sq * (1.f / ND) - mean * mean, 0.f);
    float inv  = rsqrtf(var + 1e-5f);
    float4 s4 = *reinterpret_cast<const float4*>(&sc[d4]);
    float4 b4 = *reinterpret_cast<const float4*>(&bi[d4]);
    uint2 p;
    p.x = (unsigned)f2bf((v.x - mean) * inv * s4.x + b4.x)
        | ((unsigned)f2bf((v.y - mean) * inv * s4.y + b4.y) << 16);
    p.y = (unsigned)f2bf((v.z - mean) * inv * s4.z + b4.z)
        | ((unsigned)f2bf((v.w - mean) * inv * s4.w + b4.w) << 16);
    *reinterpret_cast<uint2*>(y + (long)row * ND + d4) = p;
}

// sinusoid pos-emb (TXL order), bf16 out
__global__ __launch_bounds__(256)
void pemb_k(us* __restrict__ p)
{
    int t = blockIdx.x;
    float pos = (float)(NT - 1 - t);
    for (int j = threadIdx.x; j < ND / 2; j += 256) {
        float invf = expf(-(float)j * (9.210340371976184f / 512.0f));
        float ang  = pos * invf;
        p[(long)t * ND + j]           = f2bf(sinf(ang));
        p[(long)t * ND + ND / 2 + j]  = f2bf(cosf(ang));
    }
}

// adaptive input embedding -> h fp32
__global__ __launch_bounds__(256)
void embed_k(const int* __restrict__ x,
             const float* __restrict__ e0, const float* __restrict__ e1,
             const float* __restrict__ e2, const float* __restrict__ p1,
             const float* __restrict__ p2, float* __restrict__ h)
{
    __shared__ float e[256];
    int tok = blockIdx.x;
    int v = x[tok];
    float* outp = h + (long)tok * ND;
    if (v < 2000) {
        const float* r = e0 + (long)v * ND;
        for (int d = threadIdx.x; d < ND; d += 256) outp[d] = r[d] * 32.0f;
    } else if (v < 8000) {
        const float* r = e1 + (long)(v - 2000) * 256;
        e[threadIdx.x] = r[threadIdx.x];
        __syncthreads();
        for (int d = threadIdx.x; d < ND; d += 256) {
            float acc = 0.f;
#pragma unroll 4
            for (int i = 0; i < 256; ++i) acc += e[i] * p1[(long)i * ND + d];
            outp[d] = acc * 32.0f;
        }
    } else {
        const float* r = e2 + (long)(v - 8000) * 64;
        if (threadIdx.x < 64) e[threadIdx.x] = r[threadIdx.x];
        __syncthreads();
        for (int d = threadIdx.x; d < ND; d += 256) {
            float acc = 0.f;
#pragma unroll 4
            for (int i = 0; i < 64; ++i) acc += e[i] * p2[(long)i * ND + d];
            outp[d] = acc * 32.0f;
        }
    }
}

// ---------------------------------------------------------------- host
extern "C" void kernel_launch(void* const* d_in, const int* in_sizes, int n_in,
                              void* d_out, int out_size, void* d_ws, size_t ws_size,
                              hipStream_t stream)
{
    (void)in_sizes; (void)n_in; (void)out_size;
    const int*   x     = (const int*)  d_in[0];
    const float* emb0  = (const float*)d_in[1];
    const float* emb1  = (const float*)d_in[2];
    const float* emb2  = (const float*)d_in[3];
    const float* proj1 = (const float*)d_in[4];
    const float* proj2 = (const float*)d_in[5];
    const float* obias = (const float*)d_in[6];
    const float* rwb   = (const float*)d_in[7];
    const float* rrb   = (const float*)d_in[8];
    const float* ln1s  = (const float*)d_in[9];
    const float* ln1b  = (const float*)d_in[10];
    const float* Wq    = (const float*)d_in[11];
    const float* bq    = (const float*)d_in[12];
    const float* Wk    = (const float*)d_in[13];
    const float* bk    = (const float*)d_in[14];
    const float* Wv    = (const float*)d_in[15];
    const float* bv    = (const float*)d_in[16];
    const float* Wr    = (const float*)d_in[17];
    const float* Wo    = (const float*)d_in[18];
    const float* bo    = (const float*)d_in[19];
    const float* ln2s  = (const float*)d_in[20];
    const float* ln2b  = (const float*)d_in[21];
    const float* W1    = (const float*)d_in[22];
    const float* b1    = (const float*)d_in[23];
    const float* W2    = (const float*)d_in[24];
    const float* b2    = (const float*)d_in[25];
    float* out = (float*)d_out;

    // ---- d_out scratch (us-unit offsets); all dead before vocab GEMMs ----
    us* ob      = (us*)out;
    us* qkvbuf  = ob;                 // 6,291,456  (qw|qr|k)
    us* mid_bf  = ob +  6291456;      // 8,388,608  [2048][4096]
    us* vt_bf   = ob + 14680064;      // 2,097,152  [64][64][512]
    us* o_bf    = ob + 16777216;      // 2,097,152  [2048][1024]
    us* ain_bf  = ob + 18874368;      // 2,097,152  [2048][1024]
    us* rk_all  = ob + 20971520;      // 7,864,320  [12][640][1024] (pad rows zero)
    us* pemb_bf = ob + 28835840;      //   524,288  [512][1024]
    // fallback per-layer weight scratch (only used if ws too small)
    us* wqkv_sc = ob + 29360128;      // 3,145,728
    us* wr_sc   = ob + 32505856;      // 1,048,576
    us* wo_sc   = ob + 33554432;      // 1,048,576
    us* w1_sc   = ob + 34603008;      // 4,194,304
    us* w2_sc   = ob + 38797312;      // 4,194,304  (ends 42,991,616 us)
    float* pffn = out + 21495808;     // 8,388,608 f: [4][2048][1024] fp32 partials
    float* pwo  = out + 29884416;     // 4,194,304 f: [2][2048][1024] fp32 partials

    // ---- d_ws layout ----
    float* wsf      = (float*)d_ws;
    float* h        = wsf;                         // 2,097,152 f
    us*    h_bf     = (us*)(wsf + 2097152);
    us*    hp1_bf   = h_bf   + 2097152;            // 524,288
    us*    hp2_bf   = hp1_bf + 524288;             // 131,072
    us*    emb0_bf  = hp2_bf + 131072;             // 2048x1024 (2000 real)
    us*    emb1_bf  = emb0_bf + 2097152;           // 6144x256  (6000 real)
    us*    emb2_bf  = emb1_bf + 1572864;           // 24064x64  (24000 real)
    us*    proj1_bf = emb2_bf + 1540096;           // 256x1024
    us*    proj2_bf = proj1_bf + 262144;           // 64x1024
    float* bqkv     = (float*)(proj2_bf + 65536);  // 12*3072 f
    us*    wqkv_all = (us*)(bqkv + 36864);         // [12][3072][1024]
    us*    wr_all   = wqkv_all + (long)NL * 3072 * 1024;
    us*    wo_all   = wr_all   + (long)NL * 1024 * 1024;
    us*    w1_all   = wo_all   + (long)NL * 1024 * 1024;   // [12][4096][1024]
    us*    w2_all   = w1_all   + (long)NL * 4096 * 1024;   // [12][1024][4096]
    const bool big  = ws_size >= (size_t)352273408;        // full weight cache fits

    // ---- one-time setup ----
    bcat_k<<<144, 256, 0, stream>>>(bq, bk, bv, bqkv);
    convall_k<<<5320, 256, 0, stream>>>(emb0, emb1, emb2, proj1, proj2,
                                        emb0_bf, emb1_bf, emb2_bf, proj1_bf, proj2_bf);
    pemb_k<<<NT, 256, 0, stream>>>(pemb_bf);
    rkpad12_k<<<384, 256, 0, stream>>>(rk_all);
    embed_k<<<NBT, 256, 0, stream>>>(x, emb0, emb1, emb2, proj1, proj2, h);
    if (big) {   // batched all-layer weight transpose-convert (7 launches)
        tconv_k<<<dim3(32, 32, NL), 256, 0, stream>>>(Wq, wqkv_all,           1024, 1024, 1048576, 3145728);
        tconv_k<<<dim3(32, 32, NL), 256, 0, stream>>>(Wk, wqkv_all + 1048576, 1024, 1024, 1048576, 3145728);
        tconv_k<<<dim3(32, 32, NL), 256, 0, stream>>>(Wv, wqkv_all + 2097152, 1024, 1024, 1048576, 3145728);
        tconv_k<<<dim3(32, 32, NL), 256, 0, stream>>>(Wr, wr_all, 1024, 1024, 1048576, 1048576);
        tconv_k<<<dim3(32, 32, NL), 256, 0, stream>>>(Wo, wo_all, 1024, 1024, 1048576, 1048576);
        tconv_k<<<dim3(128, 32, NL), 256, 0, stream>>>(W1, w1_all, 1024, 4096, 4194304, 4194304);
        tconv_k<<<dim3(32, 128, NL), 256, 0, stream>>>(W2, w2_all, 4096, 1024, 4194304, 4194304);
        // batched r_k for all layers: rk_all[l] = pemb @ Wr[l]
        bgemm_k<64, 64, 0, true><<<dim3(16, 8, NL), 256, 0, stream>>>(
            pemb_bf, wr_all, rk_all, nullptr, nullptr, nullptr, nullptr, nullptr,
            1024, 1024, 1024, 1024, 1024,
            1, 0, 0, 1048576, 0, RKL, 0);
    }
    // prologue: ln1 of layer 0
    ln_k<<<NBT, 256, 0, stream>>>(h, ain_bf, ln1s, ln1b);

    for (int l = 0; l < NL; ++l) {
        const us* wqkv_t = big ? wqkv_all + (long)l * 3145728 : wqkv_sc;
        const us* wo_t   = big ? wo_all   + (long)l * 1048576 : wo_sc;
        const us* w1_t   = big ? w1_all   + (long)l * 4194304 : w1_sc;
        const us* w2_t   = big ? w2_all   + (long)l * 4194304 : w2_sc;
        if (!big) {
            const long wOff = (long)l * ND * ND;
            tconv_k<<<dim3(32, 32), 256, 0, stream>>>(Wq + wOff, wqkv_sc,           1024, 1024, 0, 0);
            tconv_k<<<dim3(32, 32), 256, 0, stream>>>(Wk + wOff, wqkv_sc + 1048576, 1024, 1024, 0, 0);
            tconv_k<<<dim3(32, 32), 256, 0, stream>>>(Wv + wOff, wqkv_sc + 2097152, 1024, 1024, 0, 0);
            tconv_k<<<dim3(32, 32), 256, 0, stream>>>(Wr + wOff, wr_sc, 1024, 1024, 0, 0);
            tconv_k<<<dim3(32, 32), 256, 0, stream>>>(Wo + wOff, wo_sc, 1024, 1024, 0, 0);
            tconv_k<<<dim3(128, 32), 256, 0, stream>>>(W1 + (long)l * ND * NF, w1_sc, 1024, 4096, 0, 0);
            tconv_k<<<dim3(32, 128), 256, 0, stream>>>(W2 + (long)l * ND * NF, w2_sc, 4096, 1024, 0, 0);
            bgemm_k<64, 64, 0, true><<<dim3(16, 8, 1), 256, 0, stream>>>(
                pemb_bf, wr_sc, rk_all + (long)l * RKL, nullptr, nullptr, nullptr, nullptr, nullptr,
                1024, 1024, 1024, 1024, 1024, 0, 0, 0, 0, 0, 0, 0);
        }

        // fused QKV (EPI=3): qw,qr,k into qkvbuf; v straight into vt
        bgemm_k<128, 64, 3, true><<<dim3(48, 16, 1), 256, 0, stream>>>(
            ain_bf, wqkv_t, qkvbuf, bqkv + l * 3072, nullptr, rwb, rrb, vt_bf,
            3072, 1024, 1024, 1024, 1024, 0, 0, 0, 0, 0, 0, 0);
        // fused attention (load-balanced q-tile pairing)
        fattn_k<<<dim3(4, NB * NH), 256, 0, stream>>>(
            qkvbuf, vt_bf, rk_all + (long)l * RKL, o_bf);
        // Wo split-K=2 at 128x64 tiles -> fp32 partials
        bgemm_k<128, 64, 0, false><<<dim3(16, 16, 2), 256, 0, stream>>>(
            o_bf, wo_t, pwo, nullptr, nullptr, nullptr, nullptr, nullptr,
            1024, 512, 1024, 1024, 1024,
            1, 512, 0, 512, 0, 2097152, 0);
        // h += bo + sum(pwo); ain = LN2(h)
        redln_k<2, 0><<<NBT, 256, 0, stream>>>(
            pwo, bo + l * ND, h, ain_bf, ln2s + l * ND, ln2b + l * ND);

        // FFN
        bgemm_k<128, 128, 1, true><<<dim3(32, 16, 1), 256, 0, stream>>>(
            ain_bf, w1_t, mid_bf, b1 + (long)l * NF, nullptr, nullptr, nullptr, nullptr,
            4096, 1024, 1024, 1024, 4096, 0, 0, 0, 0, 0, 0, 0);
        // FFN2 split-K=4 at 128x128 tiles -> fp32 partials
        bgemm_k<128, 128, 0, false><<<dim3(8, 16, 4), 256, 0, stream>>>(
            mid_bf, w2_t, pffn, nullptr, nullptr, nullptr, nullptr, nullptr,
            1024, 1024, 4096, 4096, 1024,
            1, 1024, 0, 1024, 0, 2097152, 0);
        // h += b2 + sum(pffn); then LN1(next layer) or bf16 convert (last)
        if (l < NL - 1)
            redln_k<4, 0><<<NBT, 256, 0, stream>>>(
                pffn, b2 + (long)l * ND, h, ain_bf,
                ln1s + (l + 1) * ND, ln1b + (l + 1) * ND);
        else
            redln_k<4, 1><<<NBT, 256, 0, stream>>>(
                pffn, b2 + (long)l * ND, h, h_bf, nullptr, nullptr);
    }

    // ---- tied adaptive-softmax output: (h @ proj^T) @ emb^T ----
    // cluster 0: cols [0,2000)
    bgemm_k<128, 64, 0, false><<<dim3(32, 16, 1), 256, 0, stream>>>(
        h_bf, emb0_bf, out, obias, nullptr, nullptr, nullptr, nullptr,
        2000, 1024, 1024, 1024, NV, 0, 0, 0, 0, 0, 0, 0);
    // cluster 1: hp1 = h @ proj1^T ; cols [2000,8000)
    bgemm_k<64, 64, 0, true><<<dim3(4, 32, 1), 256, 0, stream>>>(
        h_bf, proj1_bf, hp1_bf, nullptr, nullptr, nullptr, nullptr, nullptr,
        256, 1024, 1024, 1024, 256, 0, 0, 0, 0, 0, 0, 0);
    bgemm_k<128, 128, 0, false><<<dim3(47, 16, 1), 256, 0, stream>>>(
        hp1_bf, emb1_bf, out + 2000, obias + 2000, nullptr, nullptr, nullptr, nullptr,
        6000, 256, 256, 256, NV, 0, 0, 0, 0, 0, 0, 0);
    // cluster 2: hp2 = h @ proj2^T ; cols [8000,32000)
    bgemm_k<64, 64, 0, true><<<dim3(1, 32, 1), 256, 0, stream>>>(
        h_bf, proj2_bf, hp2_bf, nullptr, nullptr, nullptr, nullptr, nullptr,
        64, 1024, 1024, 1024, 64, 0, 0, 0, 0, 0, 0, 0);
    bgemm_k<128, 128, 0, false><<<dim3(188, 16, 1), 256, 0, stream>>>(
        hp2_bf, emb2_bf, out + 8000, obias + 8000, nullptr, nullptr, nullptr, nullptr,
        24000, 64, 64, 64, NV, 0, 0, 0, 0, 0, 0, 0);
}